// Round 4
// baseline (282.425 us; speedup 1.0000x reference)
//
#include <hip/hip_runtime.h>

// ---------- types ----------
typedef __attribute__((ext_vector_type(8))) _Float16 half8;
typedef __attribute__((ext_vector_type(2))) __fp16 half2r;   // cvt_pkrtz return type
typedef __attribute__((ext_vector_type(4))) float f32x4;

#define AS1 __attribute__((address_space(1)))
#define AS3 __attribute__((address_space(3)))

union H2U { half2r h; unsigned int u; };
union Frag { half8 v; unsigned long long d[2]; };

__device__ __forceinline__ unsigned int pk(float a, float b) {
    H2U x; x.h = __builtin_amdgcn_cvt_pkrtz(a, b); return x.u;
}

__device__ __forceinline__ void gload_lds16(const void* g, void* l) {
    __builtin_amdgcn_global_load_lds((const AS1 unsigned int*)g,
                                     (AS3 unsigned int*)l, 16, 0, 0);
}

// ---------- problem constants ----------
// M = B*T = 32768, D_STATE = 1088, D_MODEL = 1024, D_LATENT = 128
// W1/A layout (R0-proven): row n, byte = n*2176 + (k/64)*128 + ((2*(k%64)) ^ ((n&7)<<4))
#define W1_ROWB 2176           // 17 slabs * 128 B per row (f16, swizzled)
#define WS2_OFF 2228224        // 1024 * 2176
#define W2_ROWB 256            // 2 slabs * 128 B
#define A_ROWB  2176           // Af16 row: same slab layout as W_read
#define TBUF    49152          // one pipeline buffer: A 32 KB + B 16 KB

// pick the fused-add source for k-step ks
__device__ __forceinline__ void pick_w(int ks, const float* wsp, const float* whp,
                                       const float* whs, const float* wtg,
                                       const float*& wbase, int& wstr, int& wko) {
    if (ks < 8)       { wbase = wsp; wstr = 512; wko = ks * 64; }
    else if (ks < 12) { wbase = whp; wstr = 256; wko = ks * 64 - 512; }
    else if (ks < 16) { wbase = whs; wstr = 256; wko = ks * 64 - 768; }
    else              { wbase = wtg; wstr = 64;  wko = 0; }
}

// ============ prologue: convert weights to f16, pre-swizzled (R0-identical) ====
__global__ __launch_bounds__(256) void prep_w(const float* __restrict__ Wr,
                                              const float* __restrict__ Wk,
                                              const float* __restrict__ Wv,
                                              char* __restrict__ ws) {
    int id = blockIdx.x * 256 + threadIdx.x;
    if (id < 272 * 1024) {                       // W_read: 1024 x 1088
        int n = id / 272;
        int k = (id % 272) * 4;
        f32x4 w = *(const f32x4*)(Wr + (size_t)n * 1088 + k);
        uint2 q; q.x = pk(w.x, w.y); q.y = pk(w.z, w.w);
        size_t off = (size_t)n * W1_ROWB + ((k >> 6) << 7)
                   + (((k & 63) << 1) ^ ((n & 7) << 4));
        *(uint2*)(ws + off) = q;
    } else {                                     // Wk|Wv combined: 2048 x 128
        int j = id - 272 * 1024;                 // grid sized exactly
        int r = j >> 5;                          // 0..2047
        int k = (j & 31) << 2;                   // 0..124
        const float* src = (r < 1024) ? (Wk + (size_t)r * 128 + k)
                                      : (Wv + (size_t)(r - 1024) * 128 + k);
        f32x4 w = *(const f32x4*)src;
        uint2 q; q.x = pk(w.x, w.y); q.y = pk(w.z, w.w);
        size_t off = WS2_OFF + (size_t)r * W2_ROWB + ((k >> 6) << 7)
                   + (((k & 63) << 1) ^ ((r & 7) << 4));
        *(uint2*)(ws + off) = q;
    }
}

// ============ pass 1: Af16[m][k] = cvt(S + w), pre-swizzled (R0-identical) ====
__global__ __launch_bounds__(256)
void fuse_a(const float* __restrict__ S, const float* __restrict__ wsp,
            const float* __restrict__ whp, const float* __restrict__ whs,
            const float* __restrict__ wtg, char* __restrict__ a16) {
    int u = blockIdx.x * 256 + threadIdx.x;
    int row = u / 272;
    int rem = u % 272;
    int ks = rem >> 4;
    int k4 = (rem & 15) << 2;                    // 0..60 within slab

    const float* wbase; int wstr, wko;
    pick_w(ks, wsp, whp, whs, wtg, wbase, wstr, wko);

    f32x4 s4 = *(const f32x4*)(S + (size_t)row * 1088 + ks * 64 + k4);
    f32x4 w4 = *(const f32x4*)(wbase + (size_t)row * wstr + wko + k4);
    uint2 q; q.x = pk(s4.x + w4.x, s4.y + w4.y);
             q.y = pk(s4.z + w4.z, s4.w + w4.w);
    size_t off = (size_t)row * A_ROWB + (ks << 7)
               + (((k4) << 1) ^ ((row & 7) << 4));
    *(uint2*)(a16 + off) = q;
}

// ============ GEMM1: out = Af16 @ W_read^T — counted-vmcnt 3-deep pipeline ====
// BM=256, BN=128, BK=64, 512 thr (8 waves, per-wave 64x64), 3 x 48 KB LDS bufs.
// Per K-tile each WAVE issues exactly 6 global_load_lds (A:4 + B:2).
// Loop invariant at iter t: outstanding = tiles {t, t+1} (12 loads);
// vmcnt(6) retires tile t, leaves tile t+1 in flight ACROSS the barrier (T4).
__global__ __launch_bounds__(512, 2)
void gemm_read(const char* __restrict__ wsA, const char* __restrict__ wws,
               float* __restrict__ out) {
    extern __shared__ char lds[];                // 3 * TBUF = 147456 B

    int bid = blockIdx.x;
    int wg   = (bid & 7) * 128 + (bid >> 3);     // bijective XCD swizzle (1024%8==0)
    int mblk = wg >> 3, nblk = wg & 7;
    int m0 = mblk << 8, n0 = nblk << 7;          // 256-row A panel, 128-col B panel

    int tid = threadIdx.x;
    int lane = tid & 63, wid = tid >> 6;
    int wm = (wid >> 1) << 6, wn = (wid & 1) << 6;   // wave tile: 64x64
    int lp = lane & 15, lg = lane >> 4;

    f32x4 acc[4][4] = {};

    // stage K-tile T into buffer DL: A (256 rows x 128 B) then B (128 x 128 B)
#define STAGE(T, DL) do {                                                  \
        const char* garow = wsA + (size_t)m0 * A_ROWB + (size_t)(T) * 128; \
        const char* gbrow = wws + (size_t)n0 * W1_ROWB + (size_t)(T) * 128;\
        _Pragma("unroll")                                                  \
        for (int c = 0; c < 4; ++c) {                                      \
            int s = c * 8192 + wid * 1024 + lane * 16;                     \
            gload_lds16(garow + (size_t)(s >> 7) * A_ROWB + (s & 127),     \
                        (DL) + c * 8192 + wid * 1024);                     \
        }                                                                  \
        _Pragma("unroll")                                                  \
        for (int c = 0; c < 2; ++c) {                                      \
            int s = c * 8192 + wid * 1024 + lane * 16;                     \
            gload_lds16(gbrow + (size_t)(s >> 7) * W1_ROWB + (s & 127),    \
                        (DL) + 32768 + c * 8192 + wid * 1024);             \
        }                                                                  \
    } while (0)

#define COMPUTE(AL, BL) do {                                               \
        _Pragma("unroll")                                                  \
        for (int b = 0; b < 2; ++b) {                                      \
            Frag af[4], bf[4];                                             \
            _Pragma("unroll")                                              \
            for (int f = 0; f < 4; ++f) {                                  \
                int ra = wm + f * 16 + lp;  int xa = (ra & 7) << 4;        \
                af[f].d[0] = *(const unsigned long long*)((AL) + (ra << 7) + ((b * 64 + lg * 8) ^ xa));      \
                af[f].d[1] = *(const unsigned long long*)((AL) + (ra << 7) + ((b * 64 + 32 + lg * 8) ^ xa)); \
                int rb = wn + f * 16 + lp;  int xb = (rb & 7) << 4;        \
                bf[f].d[0] = *(const unsigned long long*)((BL) + (rb << 7) + ((b * 64 + lg * 8) ^ xb));      \
                bf[f].d[1] = *(const unsigned long long*)((BL) + (rb << 7) + ((b * 64 + 32 + lg * 8) ^ xb)); \
            }                                                              \
            __builtin_amdgcn_s_setprio(1);                                 \
            _Pragma("unroll")                                              \
            for (int i = 0; i < 4; ++i)                                    \
                _Pragma("unroll")                                          \
                for (int j = 0; j < 4; ++j)                                \
                    acc[i][j] = __builtin_amdgcn_mfma_f32_16x16x32_f16(af[i].v, bf[j].v, acc[i][j], 0, 0, 0); \
            __builtin_amdgcn_s_setprio(0);                                 \
        }                                                                  \
    } while (0)

    // prologue: stage tiles 0,1 into bufs 0,1 (12 loads/wave in flight)
    STAGE(0, lds);
    STAGE(1, lds + TBUF);

    for (int t = 0; t < 16; ++t) {
        // tile t ready; tile t+1 (6 loads) stays in flight across the barrier
        asm volatile("s_waitcnt vmcnt(6)" ::: "memory");
        __builtin_amdgcn_s_barrier();            // also fences buf[(t+2)%3] reuse
        if (t < 15) {
            char* nb = lds + ((t + 2) % 3) * TBUF;
            STAGE(t + 2, nb);
        }
        const char* cb = lds + (t % 3) * TBUF;
        COMPUTE(cb, cb + 32768);
    }
    // peeled tail: tile 16 is the only outstanding stage -> full drain
    asm volatile("s_waitcnt vmcnt(0)" ::: "memory");
    __builtin_amdgcn_s_barrier();
    {
        const char* cb = lds + (16 % 3) * TBUF;  // buf 1
        COMPUTE(cb, cb + 32768);
    }

    // epilogue: C[row = wm+i*16+lg*4+r][col = wn+j*16+lp]
    #pragma unroll
    for (int i = 0; i < 4; ++i)
        #pragma unroll
        for (int j = 0; j < 4; ++j) {
            int row = m0 + wm + i * 16 + (lg << 2);
            int col = n0 + wn + j * 16 + lp;
            float* p = out + (size_t)row * 1024 + col;
            #pragma unroll
            for (int r = 0; r < 4; ++r) p[(size_t)r * 1024] = acc[i][j][r];
        }
#undef STAGE
#undef COMPUTE
}

// ============ GEMM2: k = latent@Wk^T, v = latent@Wv^T (R0-identical) ====
__global__ __launch_bounds__(256, 2)
void gemm_kv(const float* __restrict__ lat, const char* __restrict__ ws2,
             float* __restrict__ outk, float* __restrict__ outv) {
    __shared__ char lds[32768];
    char* Al = lds;
    char* Bl = lds + 16384;

    int bid = blockIdx.x;
    int wg   = (bid & 7) * 512 + (bid >> 3);     // 4096 % 8 == 0
    int mblk = wg >> 4, nb = wg & 15;
    int m0 = mblk << 7;
    int nrow0 = nb << 7;                          // row in combined Wk|Wv
    float* out = (nb < 8) ? outk : outv;
    int n0 = (nb & 7) << 7;

    int tid = threadIdx.x;
    int lane = tid & 63, wid = tid >> 6;
    int wm = (wid >> 1) << 6, wn = (wid & 1) << 6;
    int lp = lane & 15, lg = lane >> 4;

    f32x4 acc[4][4] = {};

    for (int ks = 0; ks < 2; ++ks) {
        __syncthreads();
        {
            const char* wrow = ws2 + (size_t)nrow0 * W2_ROWB + ks * 128;
            #pragma unroll
            for (int c = 0; c < 4; ++c) {
                int s = c * 4096 + wid * 1024 + lane * 16;
                int n = s >> 7, cb = s & 127;
                gload_lds16(wrow + (size_t)n * W2_ROWB + cb,
                            Bl + c * 4096 + wid * 1024);
            }
        }
        #pragma unroll
        for (int i = 0; i < 8; ++i) {
            int u = i * 256 + tid;
            int row = u >> 4;
            int k4 = (u & 15) << 2;
            f32x4 s4 = *(const f32x4*)(lat + (size_t)(m0 + row) * 128 + ks * 64 + k4);
            uint2 q; q.x = pk(s4.x, s4.y); q.y = pk(s4.z, s4.w);
            *(uint2*)(Al + (row << 7) + ((k4 << 1) ^ ((row & 7) << 4))) = q;
        }
        __syncthreads();

        #pragma unroll
        for (int b = 0; b < 2; ++b) {
            Frag af[4], bf[4];
            #pragma unroll
            for (int f = 0; f < 4; ++f) {
                int ra = wm + f * 16 + lp;  int xa = (ra & 7) << 4;
                af[f].d[0] = *(const unsigned long long*)(Al + (ra << 7) + ((b * 64 + lg * 8) ^ xa));
                af[f].d[1] = *(const unsigned long long*)(Al + (ra << 7) + ((b * 64 + 32 + lg * 8) ^ xa));
                int rb = wn + f * 16 + lp;  int xb = (rb & 7) << 4;
                bf[f].d[0] = *(const unsigned long long*)(Bl + (rb << 7) + ((b * 64 + lg * 8) ^ xb));
                bf[f].d[1] = *(const unsigned long long*)(Bl + (rb << 7) + ((b * 64 + 32 + lg * 8) ^ xb));
            }
            #pragma unroll
            for (int i = 0; i < 4; ++i)
                #pragma unroll
                for (int j = 0; j < 4; ++j)
                    acc[i][j] = __builtin_amdgcn_mfma_f32_16x16x32_f16(af[i].v, bf[j].v, acc[i][j], 0, 0, 0);
        }
    }

    #pragma unroll
    for (int i = 0; i < 4; ++i)
        #pragma unroll
        for (int j = 0; j < 4; ++j) {
            int row = m0 + wm + i * 16 + (lg << 2);
            int col = n0 + wn + j * 16 + lp;
            float* p = out + (size_t)row * 1024 + col;
            #pragma unroll
            for (int r = 0; r < 4; ++r) p[(size_t)r * 1024] = acc[i][j][r];
        }
}

// ============ host ============
extern "C" void kernel_launch(void* const* d_in, const int* in_sizes, int n_in,
                              void* d_out, int out_size, void* d_ws, size_t ws_size,
                              hipStream_t stream) {
    const float* S   = (const float*)d_in[0];
    const float* wsp = (const float*)d_in[1];
    const float* whp = (const float*)d_in[2];
    const float* whs = (const float*)d_in[3];
    const float* wtg = (const float*)d_in[4];
    const float* Wr  = (const float*)d_in[5];
    // d_in[6] = cache: fully overwritten by latent -> dead input
    const float* lat = (const float*)d_in[7];
    const float* Wk  = (const float*)d_in[8];
    const float* Wv  = (const float*)d_in[9];
    float* out = (float*)d_out;
    char*  ws  = (char*)d_ws;

    // allow >64 KB dynamic LDS for gemm_read (one-time, host-side, not a stream op)
    static bool lds_init = false;
    if (!lds_init) {
        hipFuncSetAttribute(reinterpret_cast<const void*>(gemm_read),
                            hipFuncAttributeMaxDynamicSharedMemorySize, 3 * TBUF);
        lds_init = true;
    }

    // Af16 scratch lives in the v-region of d_out (128 MB >= 71 MB);
    // gemm_kv overwrites it afterwards (stream-ordered, deterministic).
    char* a16 = (char*)(out + 67108864ull);

    hipLaunchKernelGGL(prep_w, dim3(1344), dim3(256), 0, stream, Wr, Wk, Wv, ws);
    hipLaunchKernelGGL(fuse_a, dim3(34816), dim3(256), 0, stream,
                       S, wsp, whp, whs, wtg, a16);
    hipLaunchKernelGGL(gemm_read, dim3(1024), dim3(512), 3 * TBUF, stream,
                       a16, ws, out);
    hipLaunchKernelGGL(gemm_kv, dim3(4096), dim3(256), 0, stream,
                       lat, ws + WS2_OFF, out + 33554432ull, out + 67108864ull);
}

// Round 5
// 275.241 us; speedup vs baseline: 1.0261x; 1.0261x over previous
//
#include <hip/hip_runtime.h>

// ---------- types ----------
typedef __attribute__((ext_vector_type(8))) _Float16 half8;
typedef __attribute__((ext_vector_type(2))) __fp16 half2r;   // cvt_pkrtz return type
typedef __attribute__((ext_vector_type(4))) float f32x4;

#define AS1 __attribute__((address_space(1)))
#define AS3 __attribute__((address_space(3)))

union H2U { half2r h; unsigned int u; };
union Frag { half8 v; unsigned long long d[2]; };

__device__ __forceinline__ unsigned int pk(float a, float b) {
    H2U x; x.h = __builtin_amdgcn_cvt_pkrtz(a, b); return x.u;
}

__device__ __forceinline__ void gload_lds16(const void* g, void* l) {
    __builtin_amdgcn_global_load_lds((const AS1 unsigned int*)g,
                                     (AS3 unsigned int*)l, 16, 0, 0);
}

// ---------- problem constants ----------
// M = B*T = 32768, D_STATE = 1088, D_MODEL = 1024, D_LATENT = 128
// W1/A layout (R0-proven): row n, byte = n*2176 + (k/64)*128 + ((2*(k%64)) ^ ((n&7)<<4))
#define W1_ROWB 2176           // 17 slabs * 128 B per row (f16, swizzled)
#define WS2_OFF 2228224        // 1024 * 2176
#define W2_ROWB 256            // 2 slabs * 128 B
#define A_ROWB  2176           // Af16 row: same slab layout as W_read
#define TBUF    65536          // one gemm_read buffer: A 32 KB + B 32 KB

// pick the fused-add source for k-step ks
__device__ __forceinline__ void pick_w(int ks, const float* wsp, const float* whp,
                                       const float* whs, const float* wtg,
                                       const float*& wbase, int& wstr, int& wko) {
    if (ks < 8)       { wbase = wsp; wstr = 512; wko = ks * 64; }
    else if (ks < 12) { wbase = whp; wstr = 256; wko = ks * 64 - 512; }
    else if (ks < 16) { wbase = whs; wstr = 256; wko = ks * 64 - 768; }
    else              { wbase = wtg; wstr = 64;  wko = 0; }
}

// ============ prologue: convert weights to f16, pre-swizzled (R0-identical) ====
__global__ __launch_bounds__(256) void prep_w(const float* __restrict__ Wr,
                                              const float* __restrict__ Wk,
                                              const float* __restrict__ Wv,
                                              char* __restrict__ ws) {
    int id = blockIdx.x * 256 + threadIdx.x;
    if (id < 272 * 1024) {                       // W_read: 1024 x 1088
        int n = id / 272;
        int k = (id % 272) * 4;
        f32x4 w = *(const f32x4*)(Wr + (size_t)n * 1088 + k);
        uint2 q; q.x = pk(w.x, w.y); q.y = pk(w.z, w.w);
        size_t off = (size_t)n * W1_ROWB + ((k >> 6) << 7)
                   + (((k & 63) << 1) ^ ((n & 7) << 4));
        *(uint2*)(ws + off) = q;
    } else {                                     // Wk|Wv combined: 2048 x 128
        int j = id - 272 * 1024;                 // grid sized exactly
        int r = j >> 5;                          // 0..2047
        int k = (j & 31) << 2;                   // 0..124
        const float* src = (r < 1024) ? (Wk + (size_t)r * 128 + k)
                                      : (Wv + (size_t)(r - 1024) * 128 + k);
        f32x4 w = *(const f32x4*)src;
        uint2 q; q.x = pk(w.x, w.y); q.y = pk(w.z, w.w);
        size_t off = WS2_OFF + (size_t)r * W2_ROWB + ((k >> 6) << 7)
                   + (((k & 63) << 1) ^ ((r & 7) << 4));
        *(uint2*)(ws + off) = q;
    }
}

// ============ pass 1: Af16[m][k] = cvt(S + w), pre-swizzled (R0-identical) ====
__global__ __launch_bounds__(256)
void fuse_a(const float* __restrict__ S, const float* __restrict__ wsp,
            const float* __restrict__ whp, const float* __restrict__ whs,
            const float* __restrict__ wtg, char* __restrict__ a16) {
    int u = blockIdx.x * 256 + threadIdx.x;
    int row = u / 272;
    int rem = u % 272;
    int ks = rem >> 4;
    int k4 = (rem & 15) << 2;                    // 0..60 within slab

    const float* wbase; int wstr, wko;
    pick_w(ks, wsp, whp, whs, wtg, wbase, wstr, wko);

    f32x4 s4 = *(const f32x4*)(S + (size_t)row * 1088 + ks * 64 + k4);
    f32x4 w4 = *(const f32x4*)(wbase + (size_t)row * wstr + wko + k4);
    uint2 q; q.x = pk(s4.x + w4.x, s4.y + w4.y);
             q.y = pk(s4.z + w4.z, s4.w + w4.w);
    size_t off = (size_t)row * A_ROWB + (ks << 7)
               + (((k4) << 1) ^ ((row & 7) << 4));
    *(uint2*)(a16 + off) = q;
}

// ============ GEMM1: out = Af16 @ W_read^T — 256x256 tile, 8 waves of 128x64 ==
// Rationale: LDS traffic per output element drops from 6 B to 4 B per K-step
// (staging 64 KB + frag-reads 192 KB for 65536 outputs), bringing the LDS pipe
// (112 B/cyc/CU) into balance with the MFMA pipe. Counted vmcnt(8) keeps the
// next tile's 8 loads/wave in flight across the barrier (T4).
__global__ __launch_bounds__(512, 2)
void gemm_read(const char* __restrict__ wsA, const char* __restrict__ wws,
               float* __restrict__ out) {
    extern __shared__ char lds[];                // 2 * TBUF = 131072 B

    int bid = blockIdx.x;
    int wg   = (bid & 7) * 64 + (bid >> 3);      // bijective XCD swizzle (512%8==0)
    int mblk = wg >> 2, nblk = wg & 3;
    int m0 = mblk << 8, n0 = nblk << 8;          // 256-row, 256-col panels

    int tid = threadIdx.x;
    int lane = tid & 63, wid = tid >> 6;
    int wm = (wid >> 2) << 7, wn = (wid & 3) << 6;   // wave tile: 128x64
    int lp = lane & 15, lg = lane >> 4;

    f32x4 acc[8][4] = {};

    // stage K-tile T into buffer DL: A (256 rows x 128 B) + B (256 rows x 128 B)
    // per thread: 4 A-chunks + 4 B-chunks of 16 B -> 8 gload_lds per wave
#define STAGE(T, DL) do {                                                  \
        const char* garow = wsA + (size_t)m0 * A_ROWB + (size_t)(T) * 128; \
        const char* gbrow = wws + (size_t)n0 * W1_ROWB + (size_t)(T) * 128;\
        _Pragma("unroll")                                                  \
        for (int c = 0; c < 4; ++c) {                                      \
            int s = c * 8192 + tid * 16;                                   \
            gload_lds16(garow + (size_t)(s >> 7) * A_ROWB + (s & 127),     \
                        (DL) + s);                                         \
        }                                                                  \
        _Pragma("unroll")                                                  \
        for (int c = 0; c < 4; ++c) {                                      \
            int s = c * 8192 + tid * 16;                                   \
            gload_lds16(gbrow + (size_t)(s >> 7) * W1_ROWB + (s & 127),    \
                        (DL) + 32768 + s);                                 \
        }                                                                  \
    } while (0)

#define COMPUTE(AL, BL) do {                                               \
        _Pragma("unroll")                                                  \
        for (int b = 0; b < 2; ++b) {                                      \
            Frag af[8], bf[4];                                             \
            _Pragma("unroll")                                              \
            for (int f = 0; f < 8; ++f) {                                  \
                int ra = wm + f * 16 + lp;  int xa = (ra & 7) << 4;        \
                af[f].d[0] = *(const unsigned long long*)((AL) + (ra << 7) + ((b * 64 + lg * 8) ^ xa));      \
                af[f].d[1] = *(const unsigned long long*)((AL) + (ra << 7) + ((b * 64 + 32 + lg * 8) ^ xa)); \
            }                                                              \
            _Pragma("unroll")                                              \
            for (int f = 0; f < 4; ++f) {                                  \
                int rb = wn + f * 16 + lp;  int xb = (rb & 7) << 4;        \
                bf[f].d[0] = *(const unsigned long long*)((BL) + (rb << 7) + ((b * 64 + lg * 8) ^ xb));      \
                bf[f].d[1] = *(const unsigned long long*)((BL) + (rb << 7) + ((b * 64 + 32 + lg * 8) ^ xb)); \
            }                                                              \
            __builtin_amdgcn_s_setprio(1);                                 \
            _Pragma("unroll")                                              \
            for (int i = 0; i < 8; ++i)                                    \
                _Pragma("unroll")                                          \
                for (int j = 0; j < 4; ++j)                                \
                    acc[i][j] = __builtin_amdgcn_mfma_f32_16x16x32_f16(af[i].v, bf[j].v, acc[i][j], 0, 0, 0); \
            __builtin_amdgcn_s_setprio(0);                                 \
        }                                                                  \
    } while (0)

    // prologue: stage tile 0 into buf 0
    STAGE(0, lds);

    for (int t = 0; t < 17; ++t) {
        if (t < 16) {
            STAGE(t + 1, lds + ((t + 1) & 1) * TBUF);   // issue before compute
            asm volatile("s_waitcnt vmcnt(8)" ::: "memory"); // tile t ready; t+1 in flight
        } else {
            asm volatile("s_waitcnt vmcnt(0)" ::: "memory");
        }
        __builtin_amdgcn_s_barrier();            // all waves see tile t in LDS
        const char* cb = lds + (t & 1) * TBUF;
        COMPUTE(cb, cb + 32768);
        __builtin_amdgcn_s_barrier();            // buf reusable: staged again at t+2
    }

    // epilogue: C[row = wm+i*16+lg*4+r][col = wn+j*16+lp]
    #pragma unroll
    for (int i = 0; i < 8; ++i)
        #pragma unroll
        for (int j = 0; j < 4; ++j) {
            int row = m0 + wm + i * 16 + (lg << 2);
            int col = n0 + wn + j * 16 + lp;
            float* p = out + (size_t)row * 1024 + col;
            #pragma unroll
            for (int r = 0; r < 4; ++r) p[(size_t)r * 1024] = acc[i][j][r];
        }
#undef STAGE
#undef COMPUTE
}

// ============ GEMM2: k = latent@Wk^T, v = latent@Wv^T (R0-identical) ====
__global__ __launch_bounds__(256, 2)
void gemm_kv(const float* __restrict__ lat, const char* __restrict__ ws2,
             float* __restrict__ outk, float* __restrict__ outv) {
    __shared__ char lds[32768];
    char* Al = lds;
    char* Bl = lds + 16384;

    int bid = blockIdx.x;
    int wg   = (bid & 7) * 512 + (bid >> 3);     // 4096 % 8 == 0
    int mblk = wg >> 4, nb = wg & 15;
    int m0 = mblk << 7;
    int nrow0 = nb << 7;                          // row in combined Wk|Wv
    float* out = (nb < 8) ? outk : outv;
    int n0 = (nb & 7) << 7;

    int tid = threadIdx.x;
    int lane = tid & 63, wid = tid >> 6;
    int wm = (wid >> 1) << 6, wn = (wid & 1) << 6;
    int lp = lane & 15, lg = lane >> 4;

    f32x4 acc[4][4] = {};

    for (int ks = 0; ks < 2; ++ks) {
        __syncthreads();
        {
            const char* wrow = ws2 + (size_t)nrow0 * W2_ROWB + ks * 128;
            #pragma unroll
            for (int c = 0; c < 4; ++c) {
                int s = c * 4096 + wid * 1024 + lane * 16;
                int n = s >> 7, cb = s & 127;
                gload_lds16(wrow + (size_t)n * W2_ROWB + cb,
                            Bl + c * 4096 + wid * 1024);
            }
        }
        #pragma unroll
        for (int i = 0; i < 8; ++i) {
            int u = i * 256 + tid;
            int row = u >> 4;
            int k4 = (u & 15) << 2;
            f32x4 s4 = *(const f32x4*)(lat + (size_t)(m0 + row) * 128 + ks * 64 + k4);
            uint2 q; q.x = pk(s4.x, s4.y); q.y = pk(s4.z, s4.w);
            *(uint2*)(Al + (row << 7) + ((k4 << 1) ^ ((row & 7) << 4))) = q;
        }
        __syncthreads();

        #pragma unroll
        for (int b = 0; b < 2; ++b) {
            Frag af[4], bf[4];
            #pragma unroll
            for (int f = 0; f < 4; ++f) {
                int ra = wm + f * 16 + lp;  int xa = (ra & 7) << 4;
                af[f].d[0] = *(const unsigned long long*)(Al + (ra << 7) + ((b * 64 + lg * 8) ^ xa));
                af[f].d[1] = *(const unsigned long long*)(Al + (ra << 7) + ((b * 64 + 32 + lg * 8) ^ xa));
                int rb = wn + f * 16 + lp;  int xb = (rb & 7) << 4;
                bf[f].d[0] = *(const unsigned long long*)(Bl + (rb << 7) + ((b * 64 + lg * 8) ^ xb));
                bf[f].d[1] = *(const unsigned long long*)(Bl + (rb << 7) + ((b * 64 + 32 + lg * 8) ^ xb));
            }
            #pragma unroll
            for (int i = 0; i < 4; ++i)
                #pragma unroll
                for (int j = 0; j < 4; ++j)
                    acc[i][j] = __builtin_amdgcn_mfma_f32_16x16x32_f16(af[i].v, bf[j].v, acc[i][j], 0, 0, 0);
        }
    }

    #pragma unroll
    for (int i = 0; i < 4; ++i)
        #pragma unroll
        for (int j = 0; j < 4; ++j) {
            int row = m0 + wm + i * 16 + (lg << 2);
            int col = n0 + wn + j * 16 + lp;
            float* p = out + (size_t)row * 1024 + col;
            #pragma unroll
            for (int r = 0; r < 4; ++r) p[(size_t)r * 1024] = acc[i][j][r];
        }
}

// ============ host ============
extern "C" void kernel_launch(void* const* d_in, const int* in_sizes, int n_in,
                              void* d_out, int out_size, void* d_ws, size_t ws_size,
                              hipStream_t stream) {
    const float* S   = (const float*)d_in[0];
    const float* wsp = (const float*)d_in[1];
    const float* whp = (const float*)d_in[2];
    const float* whs = (const float*)d_in[3];
    const float* wtg = (const float*)d_in[4];
    const float* Wr  = (const float*)d_in[5];
    // d_in[6] = cache: fully overwritten by latent -> dead input
    const float* lat = (const float*)d_in[7];
    const float* Wk  = (const float*)d_in[8];
    const float* Wv  = (const float*)d_in[9];
    float* out = (float*)d_out;
    char*  ws  = (char*)d_ws;

    // allow >64 KB dynamic LDS for gemm_read (one-time, host-side, not a stream op)
    static bool lds_init = false;
    if (!lds_init) {
        hipFuncSetAttribute(reinterpret_cast<const void*>(gemm_read),
                            hipFuncAttributeMaxDynamicSharedMemorySize, 2 * TBUF);
        lds_init = true;
    }

    // Af16 scratch lives in the v-region of d_out (128 MB >= 71 MB);
    // gemm_kv overwrites it afterwards (stream-ordered, deterministic).
    char* a16 = (char*)(out + 67108864ull);

    hipLaunchKernelGGL(prep_w, dim3(1344), dim3(256), 0, stream, Wr, Wk, Wv, ws);
    hipLaunchKernelGGL(fuse_a, dim3(34816), dim3(256), 0, stream,
                       S, wsp, whp, whs, wtg, a16);
    hipLaunchKernelGGL(gemm_read, dim3(512), dim3(512), 2 * TBUF, stream,
                       a16, ws, out);
    hipLaunchKernelGGL(gemm_kv, dim3(4096), dim3(256), 0, stream,
                       lat, ws + WS2_OFF, out + 33554432ull, out + 67108864ull);
}